// Round 4
// baseline (272.509 us; speedup 1.0000x reference)
//
#include <hip/hip_runtime.h>
#include <math.h>

#define NEG_INF (-INFINITY)

__device__ __forceinline__ float nll3(float l0, float l1, float l2) {
    float m = fmaxf(l0, fmaxf(l1, l2));
    float e0 = __expf(l0 - m);
    float e1 = __expf(l1 - m);
    float e2 = __expf(l2 - m);
    return __logf(e0 + e1 + e2) - (l0 - m);
}

// ---------------------------------------------------------------------------
// Barrier-free per-wave negative focal loss.
// Each wave owns a (TD x ROWS x WL) strip (WL = min(W,64), ROWS = 64/WL) and
// slides along d. Per step: 3 h-rows of nll (9 independent coalesced loads),
// w-window max via lane shuffles, 3-deep register window along d for the
// 3x3x3 NMS. Next-plane loads are issued before consuming the current plane
// (register pipeline). No LDS, no __syncthreads.
// ---------------------------------------------------------------------------
template<int TD, int D, int H, int W>
__device__ void neg_wave(int wv, int lane,
                         const float* __restrict__ logit,
                         const float* __restrict__ pg,
                         float* __restrict__ out) {
    constexpr int WL = (W < 64) ? W : 64;
    constexpr int ROWS = 64 / WL;
    constexpr int HG = H / ROWS;
    constexpr int DT = D / TD;
    const int w = lane % WL;

    int t = wv;
    const int hg = t % HG; t /= HG;
    const int dt = t % DT; t /= DT;
    const int ba = t;                      // b*3 + a  (A == 3)
    const int a = ba % 3, b = ba / 3;
    const int h = hg * ROWS + lane / WL;
    const int d0 = dt * TD;

    const long S = (long)D * H * W;
    const float* lb  = logit + ((long)b * 9 + a) * S;   // class-0 plane (NCLS*A=9)
    const long  cs   = 3 * S;                           // A*S
    const float* pgb = pg + (long)ba * S;

    bool hv[3]; int hoff[3];
    #pragma unroll
    for (int j = 0; j < 3; ++j) {
        int hh = h - 1 + j;
        hv[j] = (hh >= 0) && (hh < H);
        hoff[j] = hh * W + w;              // only used when hv[j]
    }

    float cur[3][3] = {}, nxt[3][3] = {};
    bool dv_cur, dv_nxt;

    // prologue: load plane d0-1
    {
        const int d = d0 - 1;
        dv_cur = (d >= 0);
        if (dv_cur) {
            const float* p0 = lb + (long)d * (H * W);
            #pragma unroll
            for (int j = 0; j < 3; ++j) if (hv[j]) {
                const float* p = p0 + hoff[j];
                cur[j][0] = p[0]; cur[j][1] = p[cs]; cur[j][2] = p[2 * cs];
            }
        }
    }

    float vm0 = NEG_INF, vm1 = NEG_INF, c1 = 0.f;
    float pg_cur = 0.f, pg_nxt = 0.f;
    float loss = 0.f, cnt = 0.f;

    for (int s = 0; s <= TD + 1; ++s) {
        const int d = d0 - 1 + s;

        // issue loads for plane d+1 and pg prefetch for plane d (independent
        // of this step's compute -> latency overlapped)
        const int dn = d + 1;
        dv_nxt = (dn < D);                 // dn >= 0 always (s >= 0 => dn >= d0)
        if (s <= TD) {
            if (dv_nxt) {
                const float* p0 = lb + (long)dn * (H * W);
                #pragma unroll
                for (int j = 0; j < 3; ++j) if (hv[j]) {
                    const float* p = p0 + hoff[j];
                    nxt[j][0] = p[0]; nxt[j][1] = p[cs]; nxt[j][2] = p[2 * cs];
                }
            }
            if (s >= 1 && d < D)
                pg_nxt = pgb[((long)d * H + h) * W + w];
        }

        // compute this plane's 3 nll rows + w-window maxes
        float nv[3], rm[3];
        #pragma unroll
        for (int j = 0; j < 3; ++j)
            nv[j] = (dv_cur && hv[j]) ? nll3(cur[j][0], cur[j][1], cur[j][2])
                                      : NEG_INF;
        #pragma unroll
        for (int j = 0; j < 3; ++j) {
            float lf = __shfl(nv[j], lane - 1);
            float rt = __shfl(nv[j], lane + 1);
            lf = (w == 0)      ? NEG_INF : lf;
            rt = (w == WL - 1) ? NEG_INF : rt;
            rm[j] = fmaxf(nv[j], fmaxf(lf, rt));
        }
        float vm2 = fmaxf(rm[0], fmaxf(rm[1], rm[2]));
        float cc  = nv[1];

        if (s >= 2) {                      // emit center plane dc = d-1
            if (pg_cur == -1.0f) {
                float mp = fmaxf(vm0, fmaxf(vm1, vm2));
                if (mp == c1) {
                    float pn = __expf(-c1);
                    float wn = (1.f - pn) * (1.f - pn);
                    loss += c1 * wn;
                    cnt  += wn;
                }
            }
        }
        vm0 = vm1; vm1 = vm2; c1 = cc;
        pg_cur = pg_nxt;
        dv_cur = dv_nxt;
        #pragma unroll
        for (int j = 0; j < 3; ++j) {
            cur[j][0] = nxt[j][0]; cur[j][1] = nxt[j][1]; cur[j][2] = nxt[j][2];
        }
    }

    // wave reduce + one atomic pair per wave
    #pragma unroll
    for (int off = 32; off > 0; off >>= 1) {
        loss += __shfl_down(loss, off);
        cnt  += __shfl_down(cnt, off);
    }
    if (lane == 0) {
        atomicAdd(&out[1], loss);
        atomicAdd(&out[3], cnt);
    }
}

// ---------------------------------------------------------------------------
// Positive gathers for one level: one wave, B*P = 512 items, 8 per lane.
// ---------------------------------------------------------------------------
__device__ void pos_wave(int lane,
                         const float* __restrict__ logit,
                         const float* __restrict__ prob_gt,
                         const int* __restrict__ coord,
                         const float* __restrict__ wcls,
                         float* __restrict__ out,
                         int D, int H, int W) {
    const int A = 3, P = 128;
    const long S = (long)D * H * W;
    float loss = 0.f, cnt = 0.f;
    for (int i = lane; i < 4 * P; i += 64) {
        const int b = i / P;
        const int* c = coord + (long)i * 4;
        const int a = c[0];
        if (a > -1) {
            const int d = c[1], h = c[2], w = c[3];
            const long s = ((long)d * H + h) * W + w;
            const int cls = (int)prob_gt[((long)b * A + a) * S + s];
            const float* lp = logit + ((long)b * 3 * A + a) * S + s;
            float l0 = lp[0];
            float l1 = lp[(long)A * S];
            float l2 = lp[2L * A * S];
            float m = fmaxf(l0, fmaxf(l1, l2));
            float e0 = __expf(l0 - m);
            float e1 = __expf(l1 - m);
            float e2 = __expf(l2 - m);
            float lsum = __logf(e0 + e1 + e2);
            float lc = (cls == 0) ? l0 : ((cls == 1) ? l1 : l2);
            float lpc = (lc - m) - lsum;
            float pt = __expf(lpc);
            float wp = (1.f - pt) * (1.f - pt) * wcls[cls];
            loss += (-lpc) * wp;
            cnt += wp;
        }
    }
    #pragma unroll
    for (int off = 32; off > 0; off >>= 1) {
        loss += __shfl_down(loss, off);
        cnt  += __shfl_down(cnt, off);
    }
    if (lane == 0) {
        atomicAdd(&out[0], loss);
        atomicAdd(&out[2], cnt);
    }
}

// ---------------------------------------------------------------------------
// Single launch, wave-indexed work split. No barriers anywhere, so divergent
// wave roles inside one block are safe.
//   level0 neg: TD=8 -> 12 * 64(hg) * 8(dt) = 6144 waves
//   level1 neg: TD=8 -> 12 * 16(hg) * 4(dt) =  768 waves
//   + 2 pos waves
// ---------------------------------------------------------------------------
#define G0 6144
#define G1 768

__global__ __launch_bounds__(256, 4)
void mega_kernel(const float* __restrict__ logit0,
                 const float* __restrict__ logit1,
                 const float* __restrict__ pg0,
                 const float* __restrict__ pg1,
                 const int* __restrict__ coord0,
                 const int* __restrict__ coord1,
                 const float* __restrict__ wcls,
                 float* __restrict__ out) {
    const int gw = blockIdx.x * 4 + (threadIdx.x >> 6);
    const int lane = threadIdx.x & 63;
    if (gw < G0) {
        neg_wave<8, 64, 64, 64>(gw, lane, logit0, pg0, out);
    } else if (gw < G0 + G1) {
        neg_wave<8, 32, 32, 32>(gw - G0, lane, logit1, pg1, out);
    } else if (gw == G0 + G1) {
        pos_wave(lane, logit0, pg0, coord0, wcls, out, 64, 64, 64);
    } else if (gw == G0 + G1 + 1) {
        pos_wave(lane, logit1, pg1, coord1, wcls, out, 32, 32, 32);
    }
}

extern "C" void kernel_launch(void* const* d_in, const int* in_sizes, int n_in,
                              void* d_out, int out_size, void* d_ws, size_t ws_size,
                              hipStream_t stream) {
    const float* logit0   = (const float*)d_in[0];
    const float* logit1   = (const float*)d_in[1];
    const float* prob_gt0 = (const float*)d_in[2];
    const float* prob_gt1 = (const float*)d_in[3];
    const int*   coord0   = (const int*)d_in[4];
    const int*   coord1   = (const int*)d_in[5];
    const float* wcls     = (const float*)d_in[6];
    float* out = (float*)d_out;

    hipMemsetAsync(out, 0, 4 * sizeof(float), stream);

    const int total_waves = G0 + G1 + 2;          // 6914
    const int blocks = (total_waves + 3) / 4;     // 1729
    mega_kernel<<<blocks, 256, 0, stream>>>(
        logit0, logit1, prob_gt0, prob_gt1, coord0, coord1, wcls, out);
}

// Round 5
// 106.104 us; speedup vs baseline: 2.5683x; 2.5683x over previous
//
#include <hip/hip_runtime.h>
#include <math.h>

#define NEG_INF (-INFINITY)

__device__ __forceinline__ float nll3(float l0, float l1, float l2) {
    float m = fmaxf(l0, fmaxf(l1, l2));
    float e0 = __expf(l0 - m);
    float e1 = __expf(l1 - m);
    float e2 = __expf(l2 - m);
    return __logf(e0 + e1 + e2) - (l0 - m);
}

// ---------------------------------------------------------------------------
// Separable, barrier-free, atomic-free negative focal loss strip.
// A "unit" is WL lanes covering one w-row (WL == W). It owns an
// (TD x NR x WL) output strip and slides along d. Per d-plane:
//   - NR+2 input rows: 1 nll3 each (separable trick: row-max first)
//   - row-max via 2 lane shuffles (w-edges masked)
//   - plane-max for output row r = max(rm[r], rm[r+1], rm[r+2])
//   - 3-deep register window along d completes the 3x3x3 NMS max
// Next plane's 3*(NR+2) loads are issued before current-plane compute.
// Partial (loss,cnt) goes to a PRIVATE float2 slot — no atomics at all.
// ---------------------------------------------------------------------------
template<int WL, int NR, int TD, int D, int H, int W>
__device__ void neg_strip(int uid, int lane,
                          const float* __restrict__ logit,
                          const float* __restrict__ pg,
                          float2* __restrict__ slot) {
    constexpr int NI = NR + 2;
    constexpr int HG = H / NR;
    constexpr int DT = D / TD;
    const int w = lane & (WL - 1);

    int t = uid;
    const int hg = t % HG; t /= HG;
    const int dt = t % DT; t /= DT;
    const int ba = t;                       // b*3 + a (A == 3)
    const int a = ba % 3, b = ba / 3;
    const int h0 = hg * NR, d0 = dt * TD;

    const long S = (long)D * H * W;
    const float* lb  = logit + ((long)b * 9 + a) * S;   // class-0 plane
    const long  cs   = 3 * S;                           // A*S
    const float* pgb = pg + (long)ba * S;

    bool hv[NI]; int hoff[NI];
#pragma unroll
    for (int j = 0; j < NI; ++j) {
        int hh = h0 - 1 + j;
        hv[j] = (hh >= 0) && (hh < H);
        hoff[j] = hh * W + w;
    }

    float cur[NI][3] = {}, nxt[NI][3] = {};
    float vm0[NR], vm1[NR], c1r[NR], pgc[NR] = {}, pgn[NR] = {};
#pragma unroll
    for (int r = 0; r < NR; ++r) { vm0[r] = NEG_INF; vm1[r] = NEG_INF; c1r[r] = 0.f; }

    bool dv_cur = (d0 - 1 >= 0);
    if (dv_cur) {
        const float* p0 = lb + (long)(d0 - 1) * (H * W);
#pragma unroll
        for (int j = 0; j < NI; ++j) if (hv[j]) {
            const float* p = p0 + hoff[j];
            cur[j][0] = p[0]; cur[j][1] = p[cs]; cur[j][2] = p[2 * cs];
        }
    }

    float loss = 0.f, cnt = 0.f;

#pragma unroll
    for (int s = 0; s <= TD + 1; ++s) {
        const int d = d0 - 1 + s;
        const int dn = d + 1;
        const bool dv_nxt = (dn < D);
        // issue next plane's loads + this plane's pg BEFORE current compute
        if (s <= TD) {
            if (dv_nxt) {
                const float* p0 = lb + (long)dn * (H * W);
#pragma unroll
                for (int j = 0; j < NI; ++j) if (hv[j]) {
                    const float* p = p0 + hoff[j];
                    nxt[j][0] = p[0]; nxt[j][1] = p[cs]; nxt[j][2] = p[2 * cs];
                }
            }
            if (s >= 1) {                       // d in [d0, d0+TD-1] < D
                const float* pp = pgb + (long)d * (H * W);
#pragma unroll
                for (int r = 0; r < NR; ++r)
                    pgn[r] = pp[(h0 + r) * W + w];
            }
        }

        float nv[NI], rm[NI];
#pragma unroll
        for (int j = 0; j < NI; ++j)
            nv[j] = (dv_cur && hv[j]) ? nll3(cur[j][0], cur[j][1], cur[j][2])
                                      : NEG_INF;
#pragma unroll
        for (int j = 0; j < NI; ++j) {
            float lf = __shfl(nv[j], lane - 1);
            float rt = __shfl(nv[j], lane + 1);
            lf = (w == 0)      ? NEG_INF : lf;   // masks also protect the
            rt = (w == WL - 1) ? NEG_INF : rt;   // WL=32 half-wave boundary
            rm[j] = fmaxf(nv[j], fmaxf(lf, rt));
        }
#pragma unroll
        for (int r = 0; r < NR; ++r) {
            float hw2 = fmaxf(rm[r], fmaxf(rm[r + 1], rm[r + 2]));
            float cc  = nv[r + 1];
            if (s >= 2 && pgc[r] == -1.0f) {     // center plane d0+s-2
                float mp = fmaxf(vm0[r], fmaxf(vm1[r], hw2));
                if (mp == c1r[r]) {
                    float pn = __expf(-c1r[r]);
                    float wn = (1.f - pn) * (1.f - pn);
                    loss += c1r[r] * wn;
                    cnt  += wn;
                }
            }
            vm0[r] = vm1[r]; vm1[r] = hw2; c1r[r] = cc;
        }
#pragma unroll
        for (int r = 0; r < NR; ++r) pgc[r] = pgn[r];
        dv_cur = dv_nxt;
#pragma unroll
        for (int j = 0; j < NI; ++j) {
            cur[j][0] = nxt[j][0]; cur[j][1] = nxt[j][1]; cur[j][2] = nxt[j][2];
        }
    }

#pragma unroll
    for (int off = WL / 2; off > 0; off >>= 1) {
        loss += __shfl_down(loss, off, WL);
        cnt  += __shfl_down(cnt, off, WL);
    }
    if (w == 0) slot[uid] = make_float2(loss, cnt);
}

// ---------------------------------------------------------------------------
// Positive gathers: 8 waves per level, 1 item per lane (B*P = 512).
// Partial to a private slot — no atomics.
// ---------------------------------------------------------------------------
__device__ void pos_wave8(int sub, int lane,
                          const float* __restrict__ logit,
                          const float* __restrict__ prob_gt,
                          const int* __restrict__ coord,
                          const float* __restrict__ wcls,
                          float2* __restrict__ slot,
                          int D, int H, int W) {
    const int A = 3, P = 128;
    const long S = (long)D * H * W;
    const int i = sub * 64 + lane;          // < 512
    const int b = i / P;
    const int* c = coord + (long)i * 4;
    const int a = c[0];
    float loss = 0.f, cnt = 0.f;
    if (a > -1) {
        const int d = c[1], h = c[2], w = c[3];
        const long s = ((long)d * H + h) * W + w;
        const int cls = (int)prob_gt[((long)b * A + a) * S + s];
        const float* lp = logit + ((long)b * 3 * A + a) * S + s;
        float l0 = lp[0];
        float l1 = lp[(long)A * S];
        float l2 = lp[2L * A * S];
        float m = fmaxf(l0, fmaxf(l1, l2));
        float e0 = __expf(l0 - m);
        float e1 = __expf(l1 - m);
        float e2 = __expf(l2 - m);
        float lsum = __logf(e0 + e1 + e2);
        float lc = (cls == 0) ? l0 : ((cls == 1) ? l1 : l2);
        float lpc = (lc - m) - lsum;
        float pt = __expf(lpc);
        float wp = (1.f - pt) * (1.f - pt) * wcls[cls];
        loss = (-lpc) * wp;
        cnt = wp;
    }
#pragma unroll
    for (int off = 32; off > 0; off >>= 1) {
        loss += __shfl_down(loss, off);
        cnt  += __shfl_down(cnt, off);
    }
    if (lane == 0) *slot = make_float2(loss, cnt);
}

// ---------------------------------------------------------------------------
// Work split (wave-indexed, barrier-free):
//   L0 neg: WL=64, NR=4, TD=4 -> 12*16*16 = 3072 units, 1/wave
//   L1 neg: WL=32, NR=4, TD=4 -> 12*8*8   =  768 units, 2/wave -> 384 waves
//   pos:    8 + 8 waves
// ---------------------------------------------------------------------------
#define NU0 3072
#define NW0 3072
#define NU1 768
#define NW1 384
#define NWP 16
#define TOTAL_WAVES (NW0 + NW1 + NWP)   // 3472 -> 868 blocks

__global__ __launch_bounds__(256)
void mega_kernel(const float* __restrict__ logit0,
                 const float* __restrict__ logit1,
                 const float* __restrict__ pg0,
                 const float* __restrict__ pg1,
                 const int* __restrict__ coord0,
                 const int* __restrict__ coord1,
                 const float* __restrict__ wcls,
                 float2* __restrict__ ws) {
    const int gw = blockIdx.x * 4 + (threadIdx.x >> 6);
    const int lane = threadIdx.x & 63;
    float2* wsneg = ws;
    float2* wspos = ws + (NU0 + NU1);
    if (gw < NW0) {
        neg_strip<64, 4, 4, 64, 64, 64>(gw, lane, logit0, pg0, wsneg);
    } else if (gw < NW0 + NW1) {
        const int u = (gw - NW0) * 2 + (lane >> 5);
        neg_strip<32, 4, 4, 32, 32, 32>(u, lane, logit1, pg1, wsneg + NU0);
    } else if (gw < NW0 + NW1 + 8) {
        const int sub = gw - NW0 - NW1;
        pos_wave8(sub, lane, logit0, pg0, coord0, wcls, wspos + sub, 64, 64, 64);
    } else if (gw < NW0 + NW1 + 16) {
        const int sub = gw - NW0 - NW1 - 8;
        pos_wave8(sub, lane, logit1, pg1, coord1, wcls, wspos + 8 + sub, 32, 32, 32);
    }
}

// ---------------------------------------------------------------------------
// Final reduction: one block sums all partial slots, writes out[0..3].
// ---------------------------------------------------------------------------
__global__ __launch_bounds__(256)
void final_reduce(const float2* __restrict__ ws, float* __restrict__ out) {
    const float2* wsneg = ws;
    const float2* wspos = ws + (NU0 + NU1);
    float ln = 0.f, cn = 0.f, lp = 0.f, cp = 0.f;
    for (int i = threadIdx.x; i < NU0 + NU1; i += 256) {
        float2 v = wsneg[i]; ln += v.x; cn += v.y;
    }
    if (threadIdx.x < NWP) {
        float2 v = wspos[threadIdx.x]; lp = v.x; cp = v.y;
    }
#pragma unroll
    for (int off = 32; off > 0; off >>= 1) {
        ln += __shfl_down(ln, off); cn += __shfl_down(cn, off);
        lp += __shfl_down(lp, off); cp += __shfl_down(cp, off);
    }
    __shared__ float s[4][4];
    const int wv = threadIdx.x >> 6;
    if ((threadIdx.x & 63) == 0) {
        s[wv][0] = ln; s[wv][1] = cn; s[wv][2] = lp; s[wv][3] = cp;
    }
    __syncthreads();
    if (threadIdx.x == 0) {
        float a = 0.f, b = 0.f, c = 0.f, d = 0.f;
#pragma unroll
        for (int i = 0; i < 4; ++i) {
            a += s[i][0]; b += s[i][1]; c += s[i][2]; d += s[i][3];
        }
        out[0] = c;   // loss_pos
        out[1] = a;   // loss_neg
        out[2] = d;   // count_pos
        out[3] = b;   // count_neg
    }
}

extern "C" void kernel_launch(void* const* d_in, const int* in_sizes, int n_in,
                              void* d_out, int out_size, void* d_ws, size_t ws_size,
                              hipStream_t stream) {
    const float* logit0   = (const float*)d_in[0];
    const float* logit1   = (const float*)d_in[1];
    const float* prob_gt0 = (const float*)d_in[2];
    const float* prob_gt1 = (const float*)d_in[3];
    const int*   coord0   = (const int*)d_in[4];
    const int*   coord1   = (const int*)d_in[5];
    const float* wcls     = (const float*)d_in[6];
    float* out = (float*)d_out;
    float2* ws = (float2*)d_ws;

    mega_kernel<<<TOTAL_WAVES / 4, 256, 0, stream>>>(
        logit0, logit1, prob_gt0, prob_gt1, coord0, coord1, wcls, ws);
    final_reduce<<<1, 256, 0, stream>>>(ws, out);
}